// Round 4
// baseline (747.935 us; speedup 1.0000x reference)
//
#include <hip/hip_runtime.h>
#include <hip/hip_cooperative_groups.h>

namespace cg = cooperative_groups;

#define S_Q 512
#define DIM 512
#define SCALE_F 0.04419417382415922f  // 1/sqrt(512)
#define LDS_W 520                     // LDS row stride in shorts (breaks pow2 aliasing)

typedef short short8 __attribute__((ext_vector_type(8)));
typedef float floatx4 __attribute__((ext_vector_type(4)));

__device__ __forceinline__ float wave_sum(float v) {
#pragma unroll
  for (int o = 32; o > 0; o >>= 1) v += __shfl_xor(v, o);
  return v;
}
__device__ __forceinline__ unsigned short f2bf(float f) {
  unsigned u = __float_as_uint(f);
  return (unsigned short)((u + 0x7FFFu + ((u >> 16) & 1u)) >> 16);
}
__device__ __forceinline__ float bf2f(short s) {
  return __uint_as_float(((unsigned)(unsigned short)s) << 16);
}

// ---------------------------------------------------------------------------
// K1: cross-attention partials via MFMA (round-3 version, unchanged).
// ---------------------------------------------------------------------------
__global__ __launch_bounds__(256) void k_ca_partial(
    const float* __restrict__ tgt, const float* __restrict__ qpos,
    const float* __restrict__ mem, const float* __restrict__ pos,
    unsigned short* __restrict__ part_acc, float* __restrict__ part_ms) {
  const int j = blockIdx.x;
  const int tid = threadIdx.x;
  const int w = tid >> 6, lane = tid & 63;
  __shared__ short q_hi[4][LDS_W];
  __shared__ short q_lo[4][LDS_W];
  __shared__ float p_lds[4][3][16];
  __shared__ float wacc[4][3][DIM];
  __shared__ float wms[4][3][2];

  {
    const int d0 = lane * 8;
    const int qi = j - 1 + w;
    if (w < 3 && (unsigned)qi < (unsigned)S_Q) {
      float4 t0 = *(const float4*)(tgt + (size_t)qi * DIM + d0);
      float4 t1 = *(const float4*)(tgt + (size_t)qi * DIM + d0 + 4);
      float4 q0 = *(const float4*)(qpos + (size_t)qi * DIM + d0);
      float4 q1 = *(const float4*)(qpos + (size_t)qi * DIM + d0 + 4);
      float v[8] = {t0.x + q0.x, t0.y + q0.y, t0.z + q0.z, t0.w + q0.w,
                    t1.x + q1.x, t1.y + q1.y, t1.z + q1.z, t1.w + q1.w};
      short8 hi, lo;
#pragma unroll
      for (int e = 0; e < 8; ++e) {
        unsigned short h = f2bf(v[e]);
        hi[e] = (short)h;
        lo[e] = (short)f2bf(v[e] - bf2f((short)h));
      }
      *(short8*)(&q_hi[w][d0]) = hi;
      *(short8*)(&q_lo[w][d0]) = lo;
    } else {
      short8 z = {0, 0, 0, 0, 0, 0, 0, 0};
      *(short8*)(&q_hi[w][d0]) = z;
      *(short8*)(&q_lo[w][d0]) = z;
    }
  }
  __syncthreads();

  const int arow = lane & 15;
  const int kgrp = lane >> 4;
  const int qrow = (arow < 3) ? arow : 3;
  const size_t rowoff = ((size_t)j * 64 + w * 16 + arow) * DIM;
  floatx4 accS = {0.f, 0.f, 0.f, 0.f};
#pragma unroll 4
  for (int kc = 0; kc < 16; ++kc) {
    const int col = kc * 32 + kgrp * 8;
    float4 a0 = *(const float4*)(mem + rowoff + col);
    float4 a1 = *(const float4*)(mem + rowoff + col + 4);
    float4 p0 = *(const float4*)(pos + rowoff + col);
    float4 p1 = *(const float4*)(pos + rowoff + col + 4);
    float kv[8] = {a0.x + p0.x, a0.y + p0.y, a0.z + p0.z, a0.w + p0.w,
                   a1.x + p1.x, a1.y + p1.y, a1.z + p1.z, a1.w + p1.w};
    short8 ah, al;
#pragma unroll
    for (int e = 0; e < 8; ++e) {
      unsigned short h = f2bf(kv[e]);
      ah[e] = (short)h;
      al[e] = (short)f2bf(kv[e] - bf2f((short)h));
    }
    const short8 qh = *(const short8*)(&q_hi[qrow][col]);
    const short8 ql = *(const short8*)(&q_lo[qrow][col]);
    accS = __builtin_amdgcn_mfma_f32_16x16x32_bf16(ah, qh, accS, 0, 0, 0);
    accS = __builtin_amdgcn_mfma_f32_16x16x32_bf16(al, qh, accS, 0, 0, 0);
    accS = __builtin_amdgcn_mfma_f32_16x16x32_bf16(ah, ql, accS, 0, 0, 0);
  }
  float s[4];
#pragma unroll
  for (int r = 0; r < 4; ++r) s[r] = accS[r] * SCALE_F;
  float mloc = fmaxf(fmaxf(s[0], s[1]), fmaxf(s[2], s[3]));
  mloc = fmaxf(mloc, __shfl_xor(mloc, 16));
  mloc = fmaxf(mloc, __shfl_xor(mloc, 32));
  float p[4], sloc = 0.f;
#pragma unroll
  for (int r = 0; r < 4; ++r) {
    p[r] = __expf(s[r] - mloc);
    sloc += p[r];
  }
  sloc += __shfl_xor(sloc, 16);
  sloc += __shfl_xor(sloc, 32);
  if (arow < 3) {
    *(float4*)(&p_lds[w][arow][kgrp * 4]) = make_float4(p[0], p[1], p[2], p[3]);
    if (lane < 3) {
      wms[w][lane][0] = mloc;
      wms[w][lane][1] = sloc;
    }
  }

  const int d0 = lane * 8;
  float acc[3][8];
#pragma unroll
  for (int c = 0; c < 3; ++c)
#pragma unroll
    for (int e = 0; e < 8; ++e) acc[c][e] = 0.f;
  const float* mb = mem + ((size_t)j * 64 + w * 16) * DIM + d0;
#pragma unroll 4
  for (int f = 0; f < 16; ++f) {
    float4 m0 = *(const float4*)(mb + (size_t)f * DIM);
    float4 m1 = *(const float4*)(mb + (size_t)f * DIM + 4);
    const float mv[8] = {m0.x, m0.y, m0.z, m0.w, m1.x, m1.y, m1.z, m1.w};
    const float w0 = p_lds[w][0][f];
    const float w1 = p_lds[w][1][f];
    const float w2 = p_lds[w][2][f];
#pragma unroll
    for (int e = 0; e < 8; ++e) {
      acc[0][e] += w0 * mv[e];
      acc[1][e] += w1 * mv[e];
      acc[2][e] += w2 * mv[e];
    }
  }

#pragma unroll
  for (int c = 0; c < 3; ++c) {
    *(float4*)(&wacc[w][c][d0]) =
        make_float4(acc[c][0], acc[c][1], acc[c][2], acc[c][3]);
    *(float4*)(&wacc[w][c][d0 + 4]) =
        make_float4(acc[c][4], acc[c][5], acc[c][6], acc[c][7]);
  }
  __syncthreads();

  const int d = tid * 2;
#pragma unroll
  for (int c = 0; c < 3; ++c) {
    const int qi = j - 1 + c;
    if ((unsigned)qi >= (unsigned)S_Q) continue;
    float M = wms[0][c][0];
#pragma unroll
    for (int u = 1; u < 4; ++u) M = fmaxf(M, wms[u][c][0]);
    float S = 0.f, ax = 0.f, ay = 0.f;
#pragma unroll
    for (int u = 0; u < 4; ++u) {
      const float wg = __expf(wms[u][c][0] - M);
      S += wg * wms[u][c][1];
      const float2 a = *(const float2*)(&wacc[u][c][d]);
      ax += wg * a.x;
      ay += wg * a.y;
    }
    const size_t slot = (size_t)qi * 3 + c;
    unsigned* dst = (unsigned*)(part_acc + slot * DIM + d);
    *dst = (unsigned)f2bf(ax) | ((unsigned)f2bf(ay) << 16);
    if (tid == 0) {
      part_ms[slot * 2 + 0] = M;
      part_ms[slot * 2 + 1] = S;
    }
  }
}

// ---------------------------------------------------------------------------
// Shared GEMM pieces (unchanged).
// ---------------------------------------------------------------------------
__device__ __forceinline__ void stage_tile(const float* __restrict__ G,
                                           short* __restrict__ Ls,
                                           int rowblk, int tid) {
  const int w = tid >> 6, lane = tid & 63;
  const int col = lane * 8;
#pragma unroll
  for (int u = 0; u < 8; ++u) {
    const int row = u * 4 + w;
    const float* src = G + (size_t)(rowblk * 32 + row) * DIM + col;
    float4 a = *(const float4*)src;
    float4 b = *(const float4*)(src + 4);
    short8 s;
    s[0] = (short)f2bf(a.x); s[1] = (short)f2bf(a.y);
    s[2] = (short)f2bf(a.z); s[3] = (short)f2bf(a.w);
    s[4] = (short)f2bf(b.x); s[5] = (short)f2bf(b.y);
    s[6] = (short)f2bf(b.z); s[7] = (short)f2bf(b.w);
    *(short8*)(&Ls[row * LDS_W + col]) = s;
  }
}

template <bool RELU>
__device__ __forceinline__ void gemm_core(const short* __restrict__ As,
                                          const short* __restrict__ Ws,
                                          const float* __restrict__ bias,
                                          float* __restrict__ C, int bx, int by,
                                          int wave, int lane) {
  const int r0 = (wave >> 1) * 16, c0 = (wave & 1) * 16;
  const int frow = lane & 15, fk = (lane >> 4) * 8;
  const short* ap = &As[(r0 + frow) * LDS_W + fk];
  const short* wp = &Ws[(c0 + frow) * LDS_W + fk];
  floatx4 acc = {0.f, 0.f, 0.f, 0.f};
#pragma unroll
  for (int kc = 0; kc < 16; ++kc) {
    const short8 af = *(const short8*)(ap + kc * 32);
    const short8 wf = *(const short8*)(wp + kc * 32);
    acc = __builtin_amdgcn_mfma_f32_16x16x32_bf16(af, wf, acc, 0, 0, 0);
  }
  const int col = bx * 32 + c0 + frow;
  const int rowb = by * 32 + r0 + (lane >> 4) * 4;
  const float b = bias[col];
#pragma unroll
  for (int r = 0; r < 4; ++r) {
    float v = acc[r] + b;
    if (RELU) v = fmaxf(v, 0.f);
    C[(size_t)(rowb + r) * DIM + col] = v;
  }
}

__device__ __forceinline__ void ln_prologue(const float* __restrict__ X,
                                            const float* __restrict__ R,
                                            const float* __restrict__ g,
                                            const float* __restrict__ b,
                                            short* __restrict__ As, int by,
                                            float* x_out, int wave, int lane) {
  const int d0 = lane * 8;
  float gg[8], bb[8];
  {
    float4 g0 = *(const float4*)(g + d0);
    float4 g1 = *(const float4*)(g + d0 + 4);
    float4 b0 = *(const float4*)(b + d0);
    float4 b1 = *(const float4*)(b + d0 + 4);
    gg[0] = g0.x; gg[1] = g0.y; gg[2] = g0.z; gg[3] = g0.w;
    gg[4] = g1.x; gg[5] = g1.y; gg[6] = g1.z; gg[7] = g1.w;
    bb[0] = b0.x; bb[1] = b0.y; bb[2] = b0.z; bb[3] = b0.w;
    bb[4] = b1.x; bb[5] = b1.y; bb[6] = b1.z; bb[7] = b1.w;
  }
  for (int r = wave; r < 32; r += 4) {
    const int grow = by * 32 + r;
    const float* xp = X + (size_t)grow * DIM + d0;
    const float* rp = R + (size_t)grow * DIM + d0;
    float4 x0 = *(const float4*)xp;
    float4 x1 = *(const float4*)(xp + 4);
    float4 r0 = *(const float4*)rp;
    float4 r1 = *(const float4*)(rp + 4);
    float v[8] = {x0.x + r0.x, x0.y + r0.y, x0.z + r0.z, x0.w + r0.w,
                  x1.x + r1.x, x1.y + r1.y, x1.z + r1.z, x1.w + r1.w};
    float s = 0.f, sq = 0.f;
#pragma unroll
    for (int e = 0; e < 8; ++e) { s += v[e]; sq += v[e] * v[e]; }
#pragma unroll
    for (int o = 32; o > 0; o >>= 1) {
      s += __shfl_xor(s, o);
      sq += __shfl_xor(sq, o);
    }
    const float mean = s * (1.f / DIM);
    const float var = sq * (1.f / DIM) - mean * mean;
    const float rstd = rsqrtf(var + 1e-5f);
    float o8[8];
    short8 sv;
#pragma unroll
    for (int e = 0; e < 8; ++e) {
      o8[e] = (v[e] - mean) * rstd * gg[e] + bb[e];
      sv[e] = (short)f2bf(o8[e]);
    }
    *(short8*)(&As[r * LDS_W + d0]) = sv;
    if (x_out) {
      *(float4*)(x_out + (size_t)grow * DIM + d0) =
          make_float4(o8[0], o8[1], o8[2], o8[3]);
      *(float4*)(x_out + (size_t)grow * DIM + d0 + 4) =
          make_float4(o8[4], o8[5], o8[6], o8[7]);
    }
  }
}

// ---------------------------------------------------------------------------
// k_tail: G1..G6 + addln fused into ONE cooperative kernel. 256 blocks x 256
// threads (1 block/CU, co-resident). Rationale: the 7 tail launches summed
// ~230us while their intrinsic work is ~5us each — the time was launch +
// full-drain + cold-restart overhead per stream-serialized kernel. grid.sync
// (~us) replaces each boundary. __threadfence() before/after each sync gives
// release/acquire across non-coherent per-XCD L2s (guide §6 G16).
// ---------------------------------------------------------------------------
struct TailArgs {
  const unsigned short* part_acc;
  const float* part_ms;
  const float* tgt;
  const float* ca_t2l_w; const float* ca_t2l_b;
  const float* ca_l1_w;  const float* ca_l1_b;
  const float* ca_l2_w;  const float* ca_l2_b;
  const float* ca_n2_g;  const float* ca_n2_b;
  const float* ca_n3_g;  const float* ca_n3_b;
  const float* sa_conv_w; const float* sa_conv_b;
  const float* sa_l1_w;  const float* sa_l1_b;
  const float* sa_l2_w;  const float* sa_l2_b;
  const float* sa_n1_g;  const float* sa_n1_b;
  const float* sa_n2_g;  const float* sa_n2_b;
  float* t2; float* h; float* x; float* f; float* x2; float* c;
  float* h2; float* y1; float* f2;
  float* out;
};

__global__ __launch_bounds__(256) void k_tail(TailArgs a) {
  cg::grid_group grid = cg::this_grid();
  __shared__ short Xw[40 * LDS_W];
  __shared__ short As[32 * LDS_W];
  __shared__ short Ws[32 * LDS_W];
  const int tid = threadIdx.x;
  const int bid = blockIdx.x;
  const int bx = bid & 15, by = bid >> 4;
  const int wave = tid >> 6, lane = tid & 63;
  const int d0 = lane * 8;

  // ===== S1: G1 combine partials + GEMM(ca_t2l) -> t2
  for (int r = wave; r < 32; r += 4) {
    const int i = by * 32 + r;
    const bool valid[3] = {i < S_Q - 1, true, i > 0};
    float mm[3], ss[3], M = -1e30f;
#pragma unroll
    for (int c = 0; c < 3; ++c) {
      if (valid[c]) {
        mm[c] = a.part_ms[((size_t)i * 3 + c) * 2 + 0];
        ss[c] = a.part_ms[((size_t)i * 3 + c) * 2 + 1];
        M = fmaxf(M, mm[c]);
      } else {
        mm[c] = -1e30f;
        ss[c] = 0.f;
      }
    }
    float den = 0.f, wg[3];
#pragma unroll
    for (int c = 0; c < 3; ++c) {
      wg[c] = valid[c] ? __expf(mm[c] - M) : 0.f;
      den += wg[c] * ss[c];
    }
    const float inv = 1.f / den;
    float o[8] = {0.f, 0.f, 0.f, 0.f, 0.f, 0.f, 0.f, 0.f};
#pragma unroll
    for (int c = 0; c < 3; ++c) {
      if (valid[c]) {
        const short8 pa =
            *(const short8*)(a.part_acc + ((size_t)i * 3 + c) * DIM + d0);
#pragma unroll
        for (int e = 0; e < 8; ++e) o[e] += wg[c] * bf2f(pa[e]);
      }
    }
    short8 sv;
#pragma unroll
    for (int e = 0; e < 8; ++e) sv[e] = (short)f2bf(fmaxf(o[e] * inv, 0.f));
    *(short8*)(&As[r * LDS_W + d0]) = sv;
  }
  stage_tile(a.ca_t2l_w, Ws, bx, tid);
  __syncthreads();
  gemm_core<false>(As, Ws, a.ca_t2l_b, a.t2, bx, by, wave, lane);
  __threadfence();
  grid.sync();
  __threadfence();

  // ===== S2: LN(tgt+t2) [x out] -> GEMM(ca_l1) relu -> h
  ln_prologue(a.tgt, a.t2, a.ca_n2_g, a.ca_n2_b, As, by,
              (bx == 0) ? a.x : nullptr, wave, lane);
  stage_tile(a.ca_l1_w, Ws, bx, tid);
  __syncthreads();
  gemm_core<true>(As, Ws, a.ca_l1_b, a.h, bx, by, wave, lane);
  __threadfence();
  grid.sync();
  __threadfence();

  // ===== S3: GEMM(h, ca_l2) -> f
  stage_tile(a.h, As, by, tid);
  stage_tile(a.ca_l2_w, Ws, bx, tid);
  __syncthreads();
  gemm_core<false>(As, Ws, a.ca_l2_b, a.f, bx, by, wave, lane);
  __threadfence();
  grid.sync();
  __threadfence();

  // ===== S4: LN(x+f) 40-row window [x2 out], banded attn, GEMM(sa_conv) -> c
  {
    const int wlo = (by * 32 - 4 > 0) ? by * 32 - 4 : 0;
    const int whi = (by * 32 + 35 < S_Q - 1) ? by * 32 + 35 : S_Q - 1;
    const int nw = whi - wlo + 1;
    {
      float gg[8], bb[8];
      float4 g0 = *(const float4*)(a.ca_n3_g + d0);
      float4 g1 = *(const float4*)(a.ca_n3_g + d0 + 4);
      float4 b0 = *(const float4*)(a.ca_n3_b + d0);
      float4 b1 = *(const float4*)(a.ca_n3_b + d0 + 4);
      gg[0] = g0.x; gg[1] = g0.y; gg[2] = g0.z; gg[3] = g0.w;
      gg[4] = g1.x; gg[5] = g1.y; gg[6] = g1.z; gg[7] = g1.w;
      bb[0] = b0.x; bb[1] = b0.y; bb[2] = b0.z; bb[3] = b0.w;
      bb[4] = b1.x; bb[5] = b1.y; bb[6] = b1.z; bb[7] = b1.w;
      for (int r = wave; r < nw; r += 4) {
        const int grow = wlo + r;
        const float* xp = a.x + (size_t)grow * DIM + d0;
        const float* rp = a.f + (size_t)grow * DIM + d0;
        float4 x0 = *(const float4*)xp;
        float4 x1 = *(const float4*)(xp + 4);
        float4 r0 = *(const float4*)rp;
        float4 r1 = *(const float4*)(rp + 4);
        float v[8] = {x0.x + r0.x, x0.y + r0.y, x0.z + r0.z, x0.w + r0.w,
                      x1.x + r1.x, x1.y + r1.y, x1.z + r1.z, x1.w + r1.w};
        float s = 0.f, sq = 0.f;
#pragma unroll
        for (int e = 0; e < 8; ++e) { s += v[e]; sq += v[e] * v[e]; }
#pragma unroll
        for (int o = 32; o > 0; o >>= 1) {
          s += __shfl_xor(s, o);
          sq += __shfl_xor(sq, o);
        }
        const float mean = s * (1.f / DIM);
        const float var = sq * (1.f / DIM) - mean * mean;
        const float rstd = rsqrtf(var + 1e-5f);
        float o8[8];
        short8 sv;
#pragma unroll
        for (int e = 0; e < 8; ++e) {
          o8[e] = (v[e] - mean) * rstd * gg[e] + bb[e];
          sv[e] = (short)f2bf(o8[e]);
        }
        *(short8*)(&Xw[r * LDS_W + d0]) = sv;
        if (bx == 0 && grow >= by * 32 && grow < by * 32 + 32) {
          *(float4*)(a.x2 + (size_t)grow * DIM + d0) =
              make_float4(o8[0], o8[1], o8[2], o8[3]);
          *(float4*)(a.x2 + (size_t)grow * DIM + d0 + 4) =
              make_float4(o8[4], o8[5], o8[6], o8[7]);
        }
      }
    }
    stage_tile(a.sa_conv_w, Ws, bx, tid);
    __syncthreads();

    for (int li = wave; li < 32; li += 4) {
      const int i = by * 32 + li;
      const int lq = i - wlo;
      float qv[8];
      {
        const short8 qs = *(const short8*)(&Xw[lq * LDS_W + d0]);
#pragma unroll
        for (int e = 0; e < 8; ++e) qv[e] = bf2f(qs[e]);
      }
      const int jlo = (i - 4 > 0) ? i - 4 : 0;
      const int jhi = (i + 4 < S_Q - 1) ? i + 4 : S_Q - 1;
      const int n = jhi - jlo + 1;
      float sc[9];
#pragma unroll
      for (int k = 0; k < 9; ++k) {
        if (k < n) {
          const int lk = jlo + k - wlo;
          const short8 ks = *(const short8*)(&Xw[lk * LDS_W + d0]);
          float dd = 0.f;
#pragma unroll
          for (int e = 0; e < 8; ++e) dd += qv[e] * bf2f(ks[e]);
          sc[k] = dd;
        } else {
          sc[k] = 0.f;
        }
      }
#pragma unroll
      for (int o = 32; o > 0; o >>= 1)
#pragma unroll
        for (int k = 0; k < 9; ++k) sc[k] += __shfl_xor(sc[k], o);
      float M = -1e30f;
#pragma unroll
      for (int k = 0; k < 9; ++k) {
        sc[k] *= SCALE_F;
        if (k < n) M = fmaxf(M, sc[k]);
      }
      float p[9], den = 0.f;
#pragma unroll
      for (int k = 0; k < 9; ++k) {
        p[k] = (k < n) ? __expf(sc[k] - M) : 0.f;
        den += p[k];
      }
      const float inv = 1.f / den;
      float o8[8] = {0.f, 0.f, 0.f, 0.f, 0.f, 0.f, 0.f, 0.f};
#pragma unroll
      for (int k = 0; k < 9; ++k) {
        if (k < n) {
          const int lk = jlo + k - wlo;
          const short8 ks = *(const short8*)(&Xw[lk * LDS_W + d0]);
#pragma unroll
          for (int e = 0; e < 8; ++e) o8[e] += p[k] * bf2f(ks[e]);
        }
      }
      short8 sv;
#pragma unroll
      for (int e = 0; e < 8; ++e) sv[e] = (short)f2bf(fmaxf(o8[e] * inv, 0.f));
      *(short8*)(&As[li * LDS_W + d0]) = sv;
    }
    __syncthreads();
    gemm_core<false>(As, Ws, a.sa_conv_b, a.c, bx, by, wave, lane);
  }
  __threadfence();
  grid.sync();
  __threadfence();

  // ===== S5: LN(x2+c) [y1 out] -> GEMM(sa_l1) relu -> h2
  ln_prologue(a.x2, a.c, a.sa_n1_g, a.sa_n1_b, As, by,
              (bx == 0) ? a.y1 : nullptr, wave, lane);
  stage_tile(a.sa_l1_w, Ws, bx, tid);
  __syncthreads();
  gemm_core<true>(As, Ws, a.sa_l1_b, a.h2, bx, by, wave, lane);
  __threadfence();
  grid.sync();
  __threadfence();

  // ===== S6: GEMM(h2, sa_l2) -> f2
  stage_tile(a.h2, As, by, tid);
  stage_tile(a.sa_l2_w, Ws, bx, tid);
  __syncthreads();
  gemm_core<false>(As, Ws, a.sa_l2_b, a.f2, bx, by, wave, lane);
  __threadfence();
  grid.sync();
  __threadfence();

  // ===== S7: out = LN(y1 + f2). 2 rows/block, waves 0-1.
  if (wave < 2) {
    const int row = bid * 2 + wave;
    const float4* xp = (const float4*)(a.f2 + (size_t)row * DIM + d0);
    const float4* rp = (const float4*)(a.y1 + (size_t)row * DIM + d0);
    float4 x0 = xp[0], x1 = xp[1], r0 = rp[0], r1 = rp[1];
    float v[8] = {x0.x + r0.x, x0.y + r0.y, x0.z + r0.z, x0.w + r0.w,
                  x1.x + r1.x, x1.y + r1.y, x1.z + r1.z, x1.w + r1.w};
    float s = 0.f, sq = 0.f;
#pragma unroll
    for (int e = 0; e < 8; ++e) { s += v[e]; sq += v[e] * v[e]; }
    s = wave_sum(s);
    sq = wave_sum(sq);
    const float mean = s * (1.f / DIM);
    const float var = sq * (1.f / DIM) - mean * mean;
    const float rstd = rsqrtf(var + 1e-5f);
    const float4* gp = (const float4*)(a.sa_n2_g + d0);
    const float4* bp = (const float4*)(a.sa_n2_b + d0);
    float4 g0 = gp[0], g1 = gp[1], bb0 = bp[0], bb1 = bp[1];
    float4 o0, o1;
    o0.x = (v[0] - mean) * rstd * g0.x + bb0.x;
    o0.y = (v[1] - mean) * rstd * g0.y + bb0.y;
    o0.z = (v[2] - mean) * rstd * g0.z + bb0.z;
    o0.w = (v[3] - mean) * rstd * g0.w + bb0.w;
    o1.x = (v[4] - mean) * rstd * g1.x + bb1.x;
    o1.y = (v[5] - mean) * rstd * g1.y + bb1.y;
    o1.z = (v[6] - mean) * rstd * g1.z + bb1.z;
    o1.w = (v[7] - mean) * rstd * g1.w + bb1.w;
    *(float4*)(a.out + (size_t)row * DIM + d0) = o0;
    *(float4*)(a.out + (size_t)row * DIM + d0 + 4) = o1;
  }
}

// ---------------------------------------------------------------------------
extern "C" void kernel_launch(void* const* d_in, const int* in_sizes, int n_in,
                              void* d_out, int out_size, void* d_ws, size_t ws_size,
                              hipStream_t stream) {
  const float* tgt       = (const float*)d_in[0];
  const float* memory    = (const float*)d_in[1];
  const float* pos       = (const float*)d_in[2];
  const float* qpos      = (const float*)d_in[3];
  // d_in[4] action_idx: analytically t/64, unused
  const float* ca_t2l_w  = (const float*)d_in[5];
  const float* ca_t2l_b  = (const float*)d_in[6];
  const float* ca_l1_w   = (const float*)d_in[7];
  const float* ca_l1_b   = (const float*)d_in[8];
  const float* ca_l2_w   = (const float*)d_in[9];
  const float* ca_l2_b   = (const float*)d_in[10];
  const float* ca_n2_g   = (const float*)d_in[11];
  const float* ca_n2_b   = (const float*)d_in[12];
  const float* ca_n3_g   = (const float*)d_in[13];
  const float* ca_n3_b   = (const float*)d_in[14];
  const float* sa_conv_w = (const float*)d_in[15];
  const float* sa_conv_b = (const float*)d_in[16];
  const float* sa_l1_w   = (const float*)d_in[17];
  const float* sa_l1_b   = (const float*)d_in[18];
  const float* sa_l2_w   = (const float*)d_in[19];
  const float* sa_l2_b   = (const float*)d_in[20];
  const float* sa_n1_g   = (const float*)d_in[21];
  const float* sa_n1_b   = (const float*)d_in[22];
  const float* sa_n2_g   = (const float*)d_in[23];
  const float* sa_n2_b   = (const float*)d_in[24];
  float* out = (float*)d_out;
  float* ws = (float*)d_ws;

  // workspace (floats). part region [0,396288) dead after G1; 1MB activation
  // buffers aliased by lifetime. Peak 4.73 MB.
  unsigned short* part_acc = (unsigned short*)ws;  // 512*3*512 bf16 = 1.5MB
  float* part_ms = ws + 393216;                    // 512*3*2
  float* t2 = ws + 396288;
  float* h  = ws + 658432;
  float* x  = ws + 920576;
  float* f  = ws + 0;        // after G1 (part dead)
  float* x2 = ws + 396288;   // after G2 (t2 dead)
  float* c  = ws + 658432;   // after G3 (h dead)
  float* y1 = ws + 0;        // after G4 (f dead)
  float* h2 = ws + 920576;   // after G4 (x dead)
  float* f2 = ws + 396288;   // after G5 (x2 dead)

  k_ca_partial<<<512, 256, 0, stream>>>(tgt, qpos, memory, pos, part_acc, part_ms);

  TailArgs ta;
  ta.part_acc = part_acc; ta.part_ms = part_ms; ta.tgt = tgt;
  ta.ca_t2l_w = ca_t2l_w; ta.ca_t2l_b = ca_t2l_b;
  ta.ca_l1_w = ca_l1_w;   ta.ca_l1_b = ca_l1_b;
  ta.ca_l2_w = ca_l2_w;   ta.ca_l2_b = ca_l2_b;
  ta.ca_n2_g = ca_n2_g;   ta.ca_n2_b = ca_n2_b;
  ta.ca_n3_g = ca_n3_g;   ta.ca_n3_b = ca_n3_b;
  ta.sa_conv_w = sa_conv_w; ta.sa_conv_b = sa_conv_b;
  ta.sa_l1_w = sa_l1_w;   ta.sa_l1_b = sa_l1_b;
  ta.sa_l2_w = sa_l2_w;   ta.sa_l2_b = sa_l2_b;
  ta.sa_n1_g = sa_n1_g;   ta.sa_n1_b = sa_n1_b;
  ta.sa_n2_g = sa_n2_g;   ta.sa_n2_b = sa_n2_b;
  ta.t2 = t2; ta.h = h; ta.x = x; ta.f = f; ta.x2 = x2; ta.c = c;
  ta.h2 = h2; ta.y1 = y1; ta.f2 = f2;
  ta.out = out;

  void* kparams[] = {&ta};
  hipLaunchCooperativeKernel((void*)k_tail, dim3(256), dim3(256), kparams, 0,
                             stream);
}

// Round 5
// 287.857 us; speedup vs baseline: 2.5983x; 2.5983x over previous
//
#include <hip/hip_runtime.h>

#define S_Q 512
#define DIM 512
#define SCALE_F 0.04419417382415922f  // 1/sqrt(512)
#define LDS_W 520                     // LDS row stride in shorts (breaks pow2 aliasing)

typedef short short8 __attribute__((ext_vector_type(8)));
typedef float floatx4 __attribute__((ext_vector_type(4)));

__device__ __forceinline__ float wave_sum(float v) {
#pragma unroll
  for (int o = 32; o > 0; o >>= 1) v += __shfl_xor(v, o);
  return v;
}
__device__ __forceinline__ unsigned short f2bf(float f) {
  unsigned u = __float_as_uint(f);
  return (unsigned short)((u + 0x7FFFu + ((u >> 16) & 1u)) >> 16);
}
__device__ __forceinline__ float bf2f(short s) {
  return __uint_as_float(((unsigned)(unsigned short)s) << 16);
}

// async global->LDS, 16B per lane (dest = wave-uniform base + lane*16).
__device__ __forceinline__ void gload16(const void* g, void* l) {
  __builtin_amdgcn_global_load_lds(
      (const __attribute__((address_space(1))) unsigned int*)g,
      (__attribute__((address_space(3))) unsigned int*)l, 16, 0, 0);
}

// ---------------------------------------------------------------------------
// K1: cross-attention partials. MFMA scores (round-3 structure) + QK operand
// streaming via global_load_lds double-buffer.
//
// WHY: rounds 0-3 were pinned at 53-60us regardless of structure. Little's
// law with per-wave in-flight bytes explains it: VGPR loads keep ~16x16B =
// 256B in flight per wave -> 8 waves/CU x 256B / 900ns = ~2 TB/s ceiling
// (measured 1.87). global_load_lds puts 1KB/instruction in flight with no
// VGPR cost: chunk = 4 instrs = 4KB/wave -> 32KB/CU in flight -> HBM-bound
// (~21us floor for the 128MB mem+pos stream).
//
// LDS staging is LINEAR (gload_lds requirement); the MFMA-layout read
// (16 lanes share a 32B column group) would be a 16-way bank conflict, so
// the SOURCE address is pre-swizzled with byte ^= ((frame&7)<<4) and the
// same XOR is applied on the LDS read (guide G4 canonical; 2-way = free).
// ---------------------------------------------------------------------------
__global__ __launch_bounds__(256) void k_ca_partial(
    const float* __restrict__ tgt, const float* __restrict__ qpos,
    const float* __restrict__ mem, const float* __restrict__ pos,
    unsigned short* __restrict__ part_acc, float* __restrict__ part_ms) {
  const int j = blockIdx.x;
  const int tid = threadIdx.x;
  const int w = tid >> 6, lane = tid & 63;
  __shared__ short q_hi[4][LDS_W];
  __shared__ short q_lo[4][LDS_W];
  __shared__ float stage_mem[4][2][16 * 32];  // [wave][buf][frame*32dims] fp32
  __shared__ float stage_pos[4][2][16 * 32];
  __shared__ float p_lds[4][3][16];
  __shared__ float wacc[4][3][DIM];
  __shared__ float wms[4][3][2];

  // ---- stage Q rows (hi/lo split); wave c stages query j-1+c, wave 3 zeros.
  {
    const int d0 = lane * 8;
    const int qi = j - 1 + w;
    if (w < 3 && (unsigned)qi < (unsigned)S_Q) {
      float4 t0 = *(const float4*)(tgt + (size_t)qi * DIM + d0);
      float4 t1 = *(const float4*)(tgt + (size_t)qi * DIM + d0 + 4);
      float4 q0 = *(const float4*)(qpos + (size_t)qi * DIM + d0);
      float4 q1 = *(const float4*)(qpos + (size_t)qi * DIM + d0 + 4);
      float v[8] = {t0.x + q0.x, t0.y + q0.y, t0.z + q0.z, t0.w + q0.w,
                    t1.x + q1.x, t1.y + q1.y, t1.z + q1.z, t1.w + q1.w};
      short8 hi, lo;
#pragma unroll
      for (int e = 0; e < 8; ++e) {
        unsigned short h = f2bf(v[e]);
        hi[e] = (short)h;
        lo[e] = (short)f2bf(v[e] - bf2f((short)h));
      }
      *(short8*)(&q_hi[w][d0]) = hi;
      *(short8*)(&q_lo[w][d0]) = lo;
    } else {
      short8 z = {0, 0, 0, 0, 0, 0, 0, 0};
      *(short8*)(&q_hi[w][d0]) = z;
      *(short8*)(&q_lo[w][d0]) = z;
    }
  }
  __syncthreads();  // also drains vmcnt -> clean baseline for counted waits

  // ---- QK via MFMA, operands streamed through LDS.
  // Wave w owns frames [w*16, w*16+16). Chunk kc = dims [kc*32, kc*32+32).
  // Per chunk: 4 gload16 (mem lo/hi frames, pos lo/hi frames), 1KB each.
  // Issue chunk kc+1, then s_waitcnt vmcnt(4) -> chunk kc resident.
  const int arow = lane & 15;       // frame within wave's 16
  const int kgrp = lane >> 4;       // 8-dim group within 32-dim chunk
  const int qrow = (arow < 3) ? arow : 3;
  const float* mrow = mem + ((size_t)j * 64 + w * 16) * DIM;
  const float* prow = pos + ((size_t)j * 64 + w * 16) * DIM;
  // source swizzle for the staging instructions:
  // instr covers frames f=lane>>3 (+8 for second instr); within-row 16B slot
  // (lane&7) is fetched from orig slot ((lane&7) ^ (f&7)); f&7 == lane>>3.
  const int sfrm = lane >> 3;
  const int sorg = (((lane & 7) ^ (lane >> 3)) << 4);

#define CA_ISSUE(KC, BUF)                                                    \
  do {                                                                       \
    const char* gm = (const char*)(mrow + (size_t)sfrm * DIM) + (KC)*128 + sorg; \
    const char* gp = (const char*)(prow + (size_t)sfrm * DIM) + (KC)*128 + sorg; \
    gload16(gm, (void*)&stage_mem[w][BUF][0]);                               \
    gload16(gm + 8 * DIM * 4, (void*)&stage_mem[w][BUF][256]);               \
    gload16(gp, (void*)&stage_pos[w][BUF][0]);                               \
    gload16(gp + 8 * DIM * 4, (void*)&stage_pos[w][BUF][256]);               \
  } while (0)

  CA_ISSUE(0, 0);

  // 3 independent accumulator chains (hh, lh, hl) -> pipelined MFMAs.
  floatx4 acc_hh = {0.f, 0.f, 0.f, 0.f};
  floatx4 acc_lh = {0.f, 0.f, 0.f, 0.f};
  floatx4 acc_hl = {0.f, 0.f, 0.f, 0.f};
  const int sw = (arow & 7) << 4;              // read-side swizzle
  const int rowb = arow * 128;                 // frame row byte offset
  const int cA = rowb + (((kgrp * 32) + 0) ^ sw);
  const int cB = rowb + (((kgrp * 32) + 16) ^ sw);

  for (int kc = 0; kc < 16; ++kc) {
    const int cur = kc & 1;
    if (kc < 15) {
      CA_ISSUE(kc + 1, cur ^ 1);
      asm volatile("s_waitcnt vmcnt(4)" ::: "memory");
    } else {
      asm volatile("s_waitcnt vmcnt(0)" ::: "memory");
    }
    const char* smb = (const char*)&stage_mem[w][cur][0];
    const char* spb = (const char*)&stage_pos[w][cur][0];
    const float4 mA = *(const float4*)(smb + cA);
    const float4 mB = *(const float4*)(smb + cB);
    const float4 pA = *(const float4*)(spb + cA);
    const float4 pB = *(const float4*)(spb + cB);
    float kv[8] = {mA.x + pA.x, mA.y + pA.y, mA.z + pA.z, mA.w + pA.w,
                   mB.x + pB.x, mB.y + pB.y, mB.z + pB.z, mB.w + pB.w};
    short8 ah, al;
#pragma unroll
    for (int e = 0; e < 8; ++e) {
      unsigned short h = f2bf(kv[e]);
      ah[e] = (short)h;
      al[e] = (short)f2bf(kv[e] - bf2f((short)h));
    }
    const int qcol = kc * 32 + kgrp * 8;
    const short8 qh = *(const short8*)(&q_hi[qrow][qcol]);
    const short8 ql = *(const short8*)(&q_lo[qrow][qcol]);
    acc_hh = __builtin_amdgcn_mfma_f32_16x16x32_bf16(ah, qh, acc_hh, 0, 0, 0);
    acc_lh = __builtin_amdgcn_mfma_f32_16x16x32_bf16(al, qh, acc_lh, 0, 0, 0);
    acc_hl = __builtin_amdgcn_mfma_f32_16x16x32_bf16(ah, ql, acc_hl, 0, 0, 0);
  }
#undef CA_ISSUE

  // C layout: col(query) = lane&15, row(frame) = (lane>>4)*4 + r.
  float s[4];
#pragma unroll
  for (int r = 0; r < 4; ++r)
    s[r] = (acc_hh[r] + acc_lh[r] + acc_hl[r]) * SCALE_F;
  float mloc = fmaxf(fmaxf(s[0], s[1]), fmaxf(s[2], s[3]));
  mloc = fmaxf(mloc, __shfl_xor(mloc, 16));
  mloc = fmaxf(mloc, __shfl_xor(mloc, 32));
  float p[4], sloc = 0.f;
#pragma unroll
  for (int r = 0; r < 4; ++r) {
    p[r] = __expf(s[r] - mloc);
    sloc += p[r];
  }
  sloc += __shfl_xor(sloc, 16);
  sloc += __shfl_xor(sloc, 32);
  if (arow < 3) {
    *(float4*)(&p_lds[w][arow][kgrp * 4]) = make_float4(p[0], p[1], p[2], p[3]);
    if (lane < 3) {
      wms[w][lane][0] = mloc;
      wms[w][lane][1] = sloc;
    }
  }

  // ---- PV: per-lane dims, fp32 accumulate over own wave's 16 frames.
  // Re-reads mem (L2-warm after the QK stream); overlaps other blocks' QK.
  const int d0 = lane * 8;
  float acc[3][8];
#pragma unroll
  for (int c = 0; c < 3; ++c)
#pragma unroll
    for (int e = 0; e < 8; ++e) acc[c][e] = 0.f;
  const float* mb = mem + ((size_t)j * 64 + w * 16) * DIM + d0;
#pragma unroll 4
  for (int f = 0; f < 16; ++f) {
    float4 m0 = *(const float4*)(mb + (size_t)f * DIM);
    float4 m1 = *(const float4*)(mb + (size_t)f * DIM + 4);
    const float mv[8] = {m0.x, m0.y, m0.z, m0.w, m1.x, m1.y, m1.z, m1.w};
    const float w0 = p_lds[w][0][f];
    const float w1 = p_lds[w][1][f];
    const float w2 = p_lds[w][2][f];
#pragma unroll
    for (int e = 0; e < 8; ++e) {
      acc[0][e] += w0 * mv[e];
      acc[1][e] += w1 * mv[e];
      acc[2][e] += w2 * mv[e];
    }
  }

#pragma unroll
  for (int c = 0; c < 3; ++c) {
    *(float4*)(&wacc[w][c][d0]) =
        make_float4(acc[c][0], acc[c][1], acc[c][2], acc[c][3]);
    *(float4*)(&wacc[w][c][d0 + 4]) =
        make_float4(acc[c][4], acc[c][5], acc[c][6], acc[c][7]);
  }
  __syncthreads();

  // ---- cross-wave combine; 2 dims/thread, packed dword store.
  const int d = tid * 2;
#pragma unroll
  for (int c = 0; c < 3; ++c) {
    const int qi = j - 1 + c;
    if ((unsigned)qi >= (unsigned)S_Q) continue;
    float M = wms[0][c][0];
#pragma unroll
    for (int u = 1; u < 4; ++u) M = fmaxf(M, wms[u][c][0]);
    float S = 0.f, ax = 0.f, ay = 0.f;
#pragma unroll
    for (int u = 0; u < 4; ++u) {
      const float wg = __expf(wms[u][c][0] - M);
      S += wg * wms[u][c][1];
      const float2 a = *(const float2*)(&wacc[u][c][d]);
      ax += wg * a.x;
      ay += wg * a.y;
    }
    const size_t slot = (size_t)qi * 3 + c;
    unsigned* dst = (unsigned*)(part_acc + slot * DIM + d);
    *dst = (unsigned)f2bf(ax) | ((unsigned)f2bf(ay) << 16);
    if (tid == 0) {
      part_ms[slot * 2 + 0] = M;
      part_ms[slot * 2 + 1] = S;
    }
  }
}

// ---------------------------------------------------------------------------
// Shared GEMM pieces. Tile: 32(M) x 32(N), K=512 fully LDS-resident (bf16).
// stage_tile: WAVE-COALESCED — wave w covers row 4u+w, lane covers 8
// consecutive floats at col lane*8 (adjacent lanes adjacent addresses).
// ---------------------------------------------------------------------------
__device__ __forceinline__ void stage_tile(const float* __restrict__ G,
                                           short* __restrict__ Ls,
                                           int rowblk, int tid) {
  const int w = tid >> 6, lane = tid & 63;
  const int col = lane * 8;
#pragma unroll
  for (int u = 0; u < 8; ++u) {
    const int row = u * 4 + w;
    const float* src = G + (size_t)(rowblk * 32 + row) * DIM + col;
    float4 a = *(const float4*)src;
    float4 b = *(const float4*)(src + 4);
    short8 s;
    s[0] = (short)f2bf(a.x); s[1] = (short)f2bf(a.y);
    s[2] = (short)f2bf(a.z); s[3] = (short)f2bf(a.w);
    s[4] = (short)f2bf(b.x); s[5] = (short)f2bf(b.y);
    s[6] = (short)f2bf(b.z); s[7] = (short)f2bf(b.w);
    *(short8*)(&Ls[row * LDS_W + col]) = s;
  }
}

template <bool RELU>
__device__ __forceinline__ void gemm_core(const short* __restrict__ As,
                                          const short* __restrict__ Ws,
                                          const float* __restrict__ bias,
                                          float* __restrict__ C, int bx, int by,
                                          int wave, int lane) {
  const int r0 = (wave >> 1) * 16, c0 = (wave & 1) * 16;
  const int frow = lane & 15, fk = (lane >> 4) * 8;
  const short* ap = &As[(r0 + frow) * LDS_W + fk];
  const short* wp = &Ws[(c0 + frow) * LDS_W + fk];
  floatx4 acc = {0.f, 0.f, 0.f, 0.f};
#pragma unroll
  for (int kc = 0; kc < 16; ++kc) {
    const short8 af = *(const short8*)(ap + kc * 32);
    const short8 wf = *(const short8*)(wp + kc * 32);
    acc = __builtin_amdgcn_mfma_f32_16x16x32_bf16(af, wf, acc, 0, 0, 0);
  }
  const int col = bx * 32 + c0 + frow;
  const int rowb = by * 32 + r0 + (lane >> 4) * 4;
  const float b = bias[col];
#pragma unroll
  for (int r = 0; r < 4; ++r) {
    float v = acc[r] + b;
    if (RELU) v = fmaxf(v, 0.f);
    C[(size_t)(rowb + r) * DIM + col] = v;
  }
}

// LN prologue: As[r] = bf16(LN(X[row]+R[row])*g+b) for 32 rows; optionally
// write fp32 LN result to x_out (bx==0 blocks).
__device__ __forceinline__ void ln_prologue(const float* __restrict__ X,
                                            const float* __restrict__ R,
                                            const float* __restrict__ g,
                                            const float* __restrict__ b,
                                            short* __restrict__ As, int by,
                                            float* x_out, int wave, int lane) {
  const int d0 = lane * 8;
  float gg[8], bb[8];
  {
    float4 g0 = *(const float4*)(g + d0);
    float4 g1 = *(const float4*)(g + d0 + 4);
    float4 b0 = *(const float4*)(b + d0);
    float4 b1 = *(const float4*)(b + d0 + 4);
    gg[0] = g0.x; gg[1] = g0.y; gg[2] = g0.z; gg[3] = g0.w;
    gg[4] = g1.x; gg[5] = g1.y; gg[6] = g1.z; gg[7] = g1.w;
    bb[0] = b0.x; bb[1] = b0.y; bb[2] = b0.z; bb[3] = b0.w;
    bb[4] = b1.x; bb[5] = b1.y; bb[6] = b1.z; bb[7] = b1.w;
  }
  for (int r = wave; r < 32; r += 4) {
    const int grow = by * 32 + r;
    const float* xp = X + (size_t)grow * DIM + d0;
    const float* rp = R + (size_t)grow * DIM + d0;
    float4 x0 = *(const float4*)xp;
    float4 x1 = *(const float4*)(xp + 4);
    float4 r0 = *(const float4*)rp;
    float4 r1 = *(const float4*)(rp + 4);
    float v[8] = {x0.x + r0.x, x0.y + r0.y, x0.z + r0.z, x0.w + r0.w,
                  x1.x + r1.x, x1.y + r1.y, x1.z + r1.z, x1.w + r1.w};
    float s = 0.f, sq = 0.f;
#pragma unroll
    for (int e = 0; e < 8; ++e) { s += v[e]; sq += v[e] * v[e]; }
#pragma unroll
    for (int o = 32; o > 0; o >>= 1) {
      s += __shfl_xor(s, o);
      sq += __shfl_xor(sq, o);
    }
    const float mean = s * (1.f / DIM);
    const float var = sq * (1.f / DIM) - mean * mean;
    const float rstd = rsqrtf(var + 1e-5f);
    float o8[8];
    short8 sv;
#pragma unroll
    for (int e = 0; e < 8; ++e) {
      o8[e] = (v[e] - mean) * rstd * gg[e] + bb[e];
      sv[e] = (short)f2bf(o8[e]);
    }
    *(short8*)(&As[r * LDS_W + d0]) = sv;
    if (x_out) {
      *(float4*)(x_out + (size_t)grow * DIM + d0) =
          make_float4(o8[0], o8[1], o8[2], o8[3]);
      *(float4*)(x_out + (size_t)grow * DIM + d0 + 4) =
          make_float4(o8[4], o8[5], o8[6], o8[7]);
    }
  }
}

// ---------------------------------------------------------------------------
// G1: combine partials (finish softmax) + ReLU  ->  GEMM with ca_t2l_w.
// ---------------------------------------------------------------------------
__global__ __launch_bounds__(256) void k_g1(
    const unsigned short* __restrict__ part_acc,
    const float* __restrict__ part_ms, const float* __restrict__ W,
    const float* __restrict__ bias, float* __restrict__ C) {
  __shared__ short As[32 * LDS_W];
  __shared__ short Ws[32 * LDS_W];
  const int tid = threadIdx.x;
  const int bx = blockIdx.x, by = blockIdx.y;
  const int wave = tid >> 6, lane = tid & 63;
  const int d0 = lane * 8;
  for (int r = wave; r < 32; r += 4) {
    const int i = by * 32 + r;
    const bool valid[3] = {i < S_Q - 1, true, i > 0};
    float mm[3], ss[3], M = -1e30f;
#pragma unroll
    for (int c = 0; c < 3; ++c) {
      if (valid[c]) {
        mm[c] = part_ms[((size_t)i * 3 + c) * 2 + 0];
        ss[c] = part_ms[((size_t)i * 3 + c) * 2 + 1];
        M = fmaxf(M, mm[c]);
      } else {
        mm[c] = -1e30f;
        ss[c] = 0.f;
      }
    }
    float den = 0.f, wg[3];
#pragma unroll
    for (int c = 0; c < 3; ++c) {
      wg[c] = valid[c] ? __expf(mm[c] - M) : 0.f;
      den += wg[c] * ss[c];
    }
    const float inv = 1.f / den;
    float o[8] = {0.f, 0.f, 0.f, 0.f, 0.f, 0.f, 0.f, 0.f};
#pragma unroll
    for (int c = 0; c < 3; ++c) {
      if (valid[c]) {
        const short8 pa =
            *(const short8*)(part_acc + ((size_t)i * 3 + c) * DIM + d0);
#pragma unroll
        for (int e = 0; e < 8; ++e) o[e] += wg[c] * bf2f(pa[e]);
      }
    }
    short8 sv;
#pragma unroll
    for (int e = 0; e < 8; ++e) sv[e] = (short)f2bf(fmaxf(o[e] * inv, 0.f));
    *(short8*)(&As[r * LDS_W + d0]) = sv;
  }
  stage_tile(W, Ws, bx, tid);
  __syncthreads();
  gemm_core<false>(As, Ws, bias, C, bx, by, wave, lane);
}

// ---------------------------------------------------------------------------
// G2/G5: LN(X+R) prologue (write x_out when bx==0) -> GEMM (ReLU epilogue).
// ---------------------------------------------------------------------------
__global__ __launch_bounds__(256) void k_gln(
    const float* __restrict__ X, const float* __restrict__ R,
    const float* __restrict__ g, const float* __restrict__ b,
    const float* __restrict__ W, const float* __restrict__ bias,
    float* __restrict__ C, float* __restrict__ x_out) {
  __shared__ short As[32 * LDS_W];
  __shared__ short Ws[32 * LDS_W];
  const int tid = threadIdx.x;
  const int bx = blockIdx.x, by = blockIdx.y;
  const int wave = tid >> 6, lane = tid & 63;
  ln_prologue(X, R, g, b, As, by, (bx == 0) ? x_out : nullptr, wave, lane);
  stage_tile(W, Ws, bx, tid);
  __syncthreads();
  gemm_core<true>(As, Ws, bias, C, bx, by, wave, lane);
}

// ---------------------------------------------------------------------------
// G3/G6: plain GEMM (A fp32 global), no relu.
// ---------------------------------------------------------------------------
__global__ __launch_bounds__(256) void k_gplain(
    const float* __restrict__ A, const float* __restrict__ W,
    const float* __restrict__ bias, float* __restrict__ C) {
  __shared__ short As[32 * LDS_W];
  __shared__ short Ws[32 * LDS_W];
  const int tid = threadIdx.x;
  const int bx = blockIdx.x, by = blockIdx.y;
  const int wave = tid >> 6, lane = tid & 63;
  stage_tile(A, As, by, tid);
  stage_tile(W, Ws, bx, tid);
  __syncthreads();
  gemm_core<false>(As, Ws, bias, C, bx, by, wave, lane);
}

// ---------------------------------------------------------------------------
// G4: x2 = LN(x+f) on a 40-row window (write own rows when bx==0), banded
// self-attention (+/-4) + ReLU -> GEMM with sa_conv_w.
// ---------------------------------------------------------------------------
__global__ __launch_bounds__(256) void k_g4(
    const float* __restrict__ X, const float* __restrict__ R,
    const float* __restrict__ g, const float* __restrict__ b,
    const float* __restrict__ W, const float* __restrict__ bias,
    float* __restrict__ C, float* __restrict__ x2_out) {
  __shared__ short Xw[40 * LDS_W];
  __shared__ short As[32 * LDS_W];
  __shared__ short Ws[32 * LDS_W];
  const int tid = threadIdx.x;
  const int bx = blockIdx.x, by = blockIdx.y;
  const int wave = tid >> 6, lane = tid & 63;
  const int d0 = lane * 8;
  const int wlo = (by * 32 - 4 > 0) ? by * 32 - 4 : 0;
  const int whi = (by * 32 + 35 < S_Q - 1) ? by * 32 + 35 : S_Q - 1;
  const int nw = whi - wlo + 1;

  {
    float gg[8], bb[8];
    float4 g0 = *(const float4*)(g + d0);
    float4 g1 = *(const float4*)(g + d0 + 4);
    float4 b0 = *(const float4*)(b + d0);
    float4 b1 = *(const float4*)(b + d0 + 4);
    gg[0] = g0.x; gg[1] = g0.y; gg[2] = g0.z; gg[3] = g0.w;
    gg[4] = g1.x; gg[5] = g1.y; gg[6] = g1.z; gg[7] = g1.w;
    bb[0] = b0.x; bb[1] = b0.y; bb[2] = b0.z; bb[3] = b0.w;
    bb[4] = b1.x; bb[5] = b1.y; bb[6] = b1.z; bb[7] = b1.w;
    for (int r = wave; r < nw; r += 4) {
      const int grow = wlo + r;
      const float* xp = X + (size_t)grow * DIM + d0;
      const float* rp = R + (size_t)grow * DIM + d0;
      float4 x0 = *(const float4*)xp;
      float4 x1 = *(const float4*)(xp + 4);
      float4 r0 = *(const float4*)rp;
      float4 r1 = *(const float4*)(rp + 4);
      float v[8] = {x0.x + r0.x, x0.y + r0.y, x0.z + r0.z, x0.w + r0.w,
                    x1.x + r1.x, x1.y + r1.y, x1.z + r1.z, x1.w + r1.w};
      float s = 0.f, sq = 0.f;
#pragma unroll
      for (int e = 0; e < 8; ++e) { s += v[e]; sq += v[e] * v[e]; }
#pragma unroll
      for (int o = 32; o > 0; o >>= 1) {
        s += __shfl_xor(s, o);
        sq += __shfl_xor(sq, o);
      }
      const float mean = s * (1.f / DIM);
      const float var = sq * (1.f / DIM) - mean * mean;
      const float rstd = rsqrtf(var + 1e-5f);
      float o8[8];
      short8 sv;
#pragma unroll
      for (int e = 0; e < 8; ++e) {
        o8[e] = (v[e] - mean) * rstd * gg[e] + bb[e];
        sv[e] = (short)f2bf(o8[e]);
      }
      *(short8*)(&Xw[r * LDS_W + d0]) = sv;
      if (bx == 0 && grow >= by * 32 && grow < by * 32 + 32) {
        *(float4*)(x2_out + (size_t)grow * DIM + d0) =
            make_float4(o8[0], o8[1], o8[2], o8[3]);
        *(float4*)(x2_out + (size_t)grow * DIM + d0 + 4) =
            make_float4(o8[4], o8[5], o8[6], o8[7]);
      }
    }
  }
  stage_tile(W, Ws, bx, tid);
  __syncthreads();

  for (int li = wave; li < 32; li += 4) {
    const int i = by * 32 + li;
    const int lq = i - wlo;
    float qv[8];
    {
      const short8 qs = *(const short8*)(&Xw[lq * LDS_W + d0]);
#pragma unroll
      for (int e = 0; e < 8; ++e) qv[e] = bf2f(qs[e]);
    }
    const int jlo = (i - 4 > 0) ? i - 4 : 0;
    const int jhi = (i + 4 < S_Q - 1) ? i + 4 : S_Q - 1;
    const int n = jhi - jlo + 1;
    float sc[9];
#pragma unroll
    for (int k = 0; k < 9; ++k) {
      if (k < n) {
        const int lk = jlo + k - wlo;
        const short8 ks = *(const short8*)(&Xw[lk * LDS_W + d0]);
        float dd = 0.f;
#pragma unroll
        for (int e = 0; e < 8; ++e) dd += qv[e] * bf2f(ks[e]);
        sc[k] = dd;
      } else {
        sc[k] = 0.f;
      }
    }
#pragma unroll
    for (int o = 32; o > 0; o >>= 1)
#pragma unroll
      for (int k = 0; k < 9; ++k) sc[k] += __shfl_xor(sc[k], o);
    float M = -1e30f;
#pragma unroll
    for (int k = 0; k < 9; ++k) {
      sc[k] *= SCALE_F;
      if (k < n) M = fmaxf(M, sc[k]);
    }
    float p[9], den = 0.f;
#pragma unroll
    for (int k = 0; k < 9; ++k) {
      p[k] = (k < n) ? __expf(sc[k] - M) : 0.f;
      den += p[k];
    }
    const float inv = 1.f / den;
    float o8[8] = {0.f, 0.f, 0.f, 0.f, 0.f, 0.f, 0.f, 0.f};
#pragma unroll
    for (int k = 0; k < 9; ++k) {
      if (k < n) {
        const int lk = jlo + k - wlo;
        const short8 ks = *(const short8*)(&Xw[lk * LDS_W + d0]);
#pragma unroll
        for (int e = 0; e < 8; ++e) o8[e] += p[k] * bf2f(ks[e]);
      }
    }
    short8 sv;
#pragma unroll
    for (int e = 0; e < 8; ++e) sv[e] = (short)f2bf(fmaxf(o8[e] * inv, 0.f));
    *(short8*)(&As[li * LDS_W + d0]) = sv;
  }
  __syncthreads();
  gemm_core<false>(As, Ws, bias, C, bx, by, wave, lane);
}

// ---------------------------------------------------------------------------
// Final: out = LN(y1 + f2).
// ---------------------------------------------------------------------------
__global__ __launch_bounds__(256) void k_addln(
    const float* __restrict__ X, const float* __restrict__ R,
    const float* __restrict__ g, const float* __restrict__ b,
    float* __restrict__ out) {
  const int row = blockIdx.x * 4 + (threadIdx.x >> 6);
  const int lane = threadIdx.x & 63;
  const int d = lane * 8;
  const float4* xp = (const float4*)(X + (size_t)row * DIM + d);
  const float4* rp = (const float4*)(R + (size_t)row * DIM + d);
  float4 x0 = xp[0], x1 = xp[1], r0 = rp[0], r1 = rp[1];
  float v[8] = {x0.x + r0.x, x0.y + r0.y, x0.z + r0.z, x0.w + r0.w,
                x1.x + r1.x, x1.y + r1.y, x1.z + r1.z, x1.w + r1.w};
  float s = 0.f, sq = 0.f;
#pragma unroll
  for (int e = 0; e < 8; ++e) { s += v[e]; sq += v[e] * v[e]; }
  s = wave_sum(s);
  sq = wave_sum(sq);
  const float mean = s * (1.f / DIM);
  const float var = sq * (1.f / DIM) - mean * mean;
  const float rstd = rsqrtf(var + 1e-5f);
  const float4* gp = (const float4*)(g + d);
  const float4* bp = (const float4*)(b + d);
  float4 g0 = gp[0], g1 = gp[1], bb0 = bp[0], bb1 = bp[1];
  float4 o0, o1;
  o0.x = (v[0] - mean) * rstd * g0.x + bb0.x;
  o0.y = (v[1] - mean) * rstd * g0.y + bb0.y;
  o0.z = (v[2] - mean) * rstd * g0.z + bb0.z;
  o0.w = (v[3] - mean) * rstd * g0.w + bb0.w;
  o1.x = (v[4] - mean) * rstd * g1.x + bb1.x;
  o1.y = (v[5] - mean) * rstd * g1.y + bb1.y;
  o1.z = (v[6] - mean) * rstd * g1.z + bb1.z;
  o1.w = (v[7] - mean) * rstd * g1.w + bb1.w;
  *(float4*)(out + (size_t)row * DIM + d) = o0;
  *(float4*)(out + (size_t)row * DIM + d + 4) = o1;
}

// ---------------------------------------------------------------------------
extern "C" void kernel_launch(void* const* d_in, const int* in_sizes, int n_in,
                              void* d_out, int out_size, void* d_ws, size_t ws_size,
                              hipStream_t stream) {
  const float* tgt       = (const float*)d_in[0];
  const float* memory    = (const float*)d_in[1];
  const float* pos       = (const float*)d_in[2];
  const float* qpos      = (const float*)d_in[3];
  // d_in[4] action_idx: analytically t/64, unused
  const float* ca_t2l_w  = (const float*)d_in[5];
  const float* ca_t2l_b  = (const float*)d_in[6];
  const float* ca_l1_w   = (const float*)d_in[7];
  const float* ca_l1_b   = (const float*)d_in[8];
  const float* ca_l2_w   = (const float*)d_in[9];
  const float* ca_l2_b   = (const float*)d_in[10];
  const float* ca_n2_g   = (const float*)d_in[11];
  const float* ca_n2_b   = (const float*)d_in[12];
  const float* ca_n3_g   = (const float*)d_in[13];
  const float* ca_n3_b   = (const float*)d_in[14];
  const float* sa_conv_w = (const float*)d_in[15];
  const float* sa_conv_b = (const float*)d_in[16];
  const float* sa_l1_w   = (const float*)d_in[17];
  const float* sa_l1_b   = (const float*)d_in[18];
  const float* sa_l2_w   = (const float*)d_in[19];
  const float* sa_l2_b   = (const float*)d_in[20];
  const float* sa_n1_g   = (const float*)d_in[21];
  const float* sa_n1_b   = (const float*)d_in[22];
  const float* sa_n2_g   = (const float*)d_in[23];
  const float* sa_n2_b   = (const float*)d_in[24];
  float* out = (float*)d_out;
  float* ws = (float*)d_ws;

  // workspace (floats). part region [0,396288) dead after G1; 1MB activation
  // buffers aliased by lifetime. Peak 4.73 MB.
  unsigned short* part_acc = (unsigned short*)ws;  // 512*3*512 bf16 = 1.5MB
  float* part_ms = ws + 393216;                    // 512*3*2
  float* t2 = ws + 396288;
  float* h  = ws + 658432;
  float* x  = ws + 920576;
  float* f  = ws + 0;        // after G1 (part dead)
  float* x2 = ws + 396288;   // after G2 (t2 dead)
  float* c  = ws + 658432;   // after G3 (h dead)
  float* y1 = ws + 0;        // after G4 (f dead)
  float* h2 = ws + 920576;   // after G4 (x dead)
  float* f2 = ws + 396288;   // after G5 (x2 dead)

  const dim3 gg(16, 16, 1);

  k_ca_partial<<<512, 256, 0, stream>>>(tgt, qpos, memory, pos, part_acc, part_ms);
  k_g1<<<gg, 256, 0, stream>>>(part_acc, part_ms, ca_t2l_w, ca_t2l_b, t2);
  k_gln<<<gg, 256, 0, stream>>>(tgt, t2, ca_n2_g, ca_n2_b, ca_l1_w, ca_l1_b, h, x);
  k_gplain<<<gg, 256, 0, stream>>>(h, ca_l2_w, ca_l2_b, f);
  k_g4<<<gg, 256, 0, stream>>>(x, f, ca_n3_g, ca_n3_b, sa_conv_w, sa_conv_b, c, x2);
  k_gln<<<gg, 256, 0, stream>>>(x2, c, sa_n1_g, sa_n1_b, sa_l1_w, sa_l1_b, h2, y1);
  k_gplain<<<gg, 256, 0, stream>>>(h2, sa_l2_w, sa_l2_b, f2);
  k_addln<<<128, 256, 0, stream>>>(f2, y1, sa_n2_g, sa_n2_b, out);
}